// Round 3
// baseline (1085.119 us; speedup 1.0000x reference)
//
#include <hip/hip_runtime.h>

typedef _Float16 f16;
typedef _Float16 f16x8 __attribute__((ext_vector_type(8)));
typedef float    f32x4 __attribute__((ext_vector_type(4)));

// R=256, C=256, B=1, E=768, H=12, Dh=64. scaling = (1/8)/16 = 1/128.
// token m = r*256 + i.
//
// ws layout (bytes):
#define OFF_XH   0UL           // Xh 100 MB; dead after QKV -> Sp (50 MB) -> CTXh (100 MB)
#define OFF_QN   100663296UL   // Qn token-major [m][h*64+d] f16, 100 MB
#define OFF_KN   201326592UL   // Kn same
#define OFF_VT   301989888UL   // Vt2 [h][r*64+d][j] f16, 100 MB
#define OFF_WQKV 402653184UL   // [2304][768] f16 = 3538944 B
#define OFF_WO   406192128UL   // 1179648 B
#define OFF_BQKV 407371776UL   // 2304 f32 = 9216 B
#define OFF_PH   407380992UL   // probs f16, 1.5 MB -> end 408953856 (< round-0 412 MB OK)

__global__ __launch_bounds__(256) void cast_f32_f16(const float* __restrict__ in,
                                                    f16* __restrict__ out, int n8) {
    int i = blockIdx.x * 256 + threadIdx.x;
    if (i >= n8) return;
    const float4* p = (const float4*)in;
    float4 a = p[2*i], b = p[2*i+1];
    f16x8 o;
    o[0]=(f16)a.x; o[1]=(f16)a.y; o[2]=(f16)a.z; o[3]=(f16)a.w;
    o[4]=(f16)b.x; o[5]=(f16)b.y; o[6]=(f16)b.z; o[7]=(f16)b.w;
    ((f16x8*)out)[i] = o;
}

__global__ void pack_bias(const float* __restrict__ a, const float* __restrict__ b,
                          const float* __restrict__ c, float* __restrict__ o) {
    int t = threadIdx.x;  // 768
    o[t] = a[t]; o[768 + t] = b[t]; o[1536 + t] = c[t];
}

__device__ __forceinline__ void gl_lds16(const f16* g, f16* l) {
    auto gp = (const __attribute__((address_space(1))) f16*)(g);
    auto lp = (__attribute__((address_space(3))) f16*)(l);
    __builtin_amdgcn_global_load_lds(gp, lp, 16, 0, 0);
}

enum { MODE_QKV = 0, MODE_SPLIT = 1, MODE_CTX = 2, MODE_OUT = 3 };

// Big-tile NT GEMM: C[m,n] = sum_k A[m,k]*B[n,k]. BM=BN=256, BK=64,
// 512 thr = 8 waves (4m x 2n), wave tile 64x128 (acc[4][8]).
// LDS 64 KB single-buffer, global_load_lds width=16, XOR-swizzled columns
// (verified 0 bank conflicts in round 1). kadv = element advance per BK
// step (64 for contiguous-k; 256*768 for scores, where each BK window is
// one r-slice of d=0..63 in token-major Q/K).
template<int MODE>
__global__ __launch_bounds__(512) void gemm_big(
    const f16* __restrict__ A, const f16* __restrict__ B,
    float* __restrict__ outF, f16* __restrict__ outH,
    const float* __restrict__ bias,
    int lda, int ldb, int K, long kadv)
{
    __shared__ f16 As[256 * 64];
    __shared__ f16 Bs[256 * 64];
    const int tid = threadIdx.x;
    const int wv = tid >> 6, ln = tid & 63;
    const int lrow = ln & 15, quad = ln >> 4;
    const int wm = wv >> 1, wn = wv & 1;
    const int m0 = blockIdx.y * 256;
    const int n0 = blockIdx.x * 256;
    const int z = blockIdx.z;

    if constexpr (MODE == MODE_SPLIT) {
        const int h = z >> 4, sp = z & 15;
        A += (long)h * 64 + (long)sp * 16 * 196608;
        B += (long)h * 64 + (long)sp * 16 * 196608;
    } else if constexpr (MODE == MODE_CTX) {
        A += (long)z * 65536;     // Ph head z (256 x 256)
        B += (long)z * 4194304;   // Vt2 head z (16384 x 256)
    }

    // staging: 4 rounds each for A and B; round q covers rows q*64 + wv*8 + (ln>>3)
    const int srow = wv * 8 + (ln >> 3);
    const int scol = ((ln & 7) ^ (ln >> 3)) << 3;   // row&7 == ln>>3
    const f16* ga = A + (long)(m0 + srow) * lda + scol;
    const f16* gb = B + (long)(n0 + srow) * ldb + scol;
    f16* lA = As + (wv * 64 + ln) * 8;
    f16* lB = Bs + (wv * 64 + ln) * 8;

    f32x4 acc[4][8] = {};

    for (int k0 = 0; k0 < K; k0 += 64) {
        __syncthreads();
        #pragma unroll
        for (int q = 0; q < 4; q++) {
            gl_lds16(ga + (long)q * 64 * lda, lA + q * 4096);
            gl_lds16(gb + (long)q * 64 * ldb, lB + q * 4096);
        }
        ga += kadv; gb += kadv;
        __syncthreads();
        #pragma unroll
        for (int ks = 0; ks < 2; ks++) {
            const int slot = ((ks * 4 + quad) ^ (lrow & 7)) << 3;  // un-swizzle
            f16x8 af[4], bf[8];
            #pragma unroll
            for (int i = 0; i < 4; i++)
                af[i] = *(const f16x8*)&As[(wm * 64 + i * 16 + lrow) * 64 + slot];
            #pragma unroll
            for (int j = 0; j < 8; j++)
                bf[j] = *(const f16x8*)&Bs[(wn * 128 + j * 16 + lrow) * 64 + slot];
            #pragma unroll
            for (int i = 0; i < 4; i++)
                #pragma unroll
                for (int j = 0; j < 8; j++)
                    acc[i][j] = __builtin_amdgcn_mfma_f32_16x16x32_f16(af[i], bf[j], acc[i][j], 0, 0, 0);
        }
    }

    // D-layout: col(n) = lane&15, row(m) = quad*4 + reg.
    #pragma unroll
    for (int i = 0; i < 4; i++) {
        #pragma unroll
        for (int j = 0; j < 8; j++) {
            #pragma unroll
            for (int r = 0; r < 4; r++) {
                int m = m0 + wm * 64 + i * 16 + quad * 4 + r;
                int n = n0 + wn * 128 + j * 16 + lrow;
                float v = acc[i][j][r];
                if constexpr (MODE == MODE_QKV) {
                    v += bias[n];
                    if (n0 < 768) {
                        outH[(long)m * 768 + n] = (f16)(v * (1.0f / 128.0f));      // Qn
                    } else if (n0 < 1536) {
                        (outH + 50331648L)[(long)m * 768 + (n - 768)] = (f16)v;    // Kn
                    } else {
                        int np = n - 1536;  // h=np>>6, d=np&63, r=m>>8, j=m&255
                        (outH + 100663296L)[(((long)((np >> 6) * 256 + (m >> 8)) << 6) + (np & 63)) * 256 + (m & 255)] = (f16)v;
                    }
                } else if constexpr (MODE == MODE_SPLIT) {
                    outF[(long)(z & 15) * 786432 + (long)(z >> 4) * 65536 + m * 256 + n] = v;
                } else if constexpr (MODE == MODE_CTX) {
                    // m=i, n=r*64+d -> CTXh[(r*256+i)*768 + h*64+d]
                    outH[((long)((n >> 6) * 256 + m)) * 768 + z * 64 + (n & 63)] = (f16)v;
                } else {  // MODE_OUT
                    outF[(long)m * 768 + n] = v + bias[n];
                }
            }
        }
    }
}

// 16-way split-K reduce + shared softmax. One block per (h,i) row.
__global__ __launch_bounds__(256) void softmax_k(const float* __restrict__ Sp,
                                                 float* __restrict__ pOut,
                                                 f16* __restrict__ Ph) {
    __shared__ float red[8];
    const int row = blockIdx.x;   // h*256 + i
    const int t = threadIdx.x;    // j
    float v = 0.f;
    #pragma unroll
    for (int s = 0; s < 16; s++)
        v += Sp[(long)s * 786432 + (long)row * 256 + t];
    float mx = v;
    #pragma unroll
    for (int o = 32; o; o >>= 1) mx = fmaxf(mx, __shfl_xor(mx, o, 64));
    if ((t & 63) == 0) red[t >> 6] = mx;
    __syncthreads();
    mx = fmaxf(fmaxf(red[0], red[1]), fmaxf(red[2], red[3]));
    float e = expf(v - mx);
    float s = e;
    #pragma unroll
    for (int o = 32; o; o >>= 1) s += __shfl_xor(s, o, 64);
    if ((t & 63) == 0) red[4 + (t >> 6)] = s;
    __syncthreads();
    s = red[4] + red[5] + red[6] + red[7];
    float p = e / s;
    pOut[(long)row * 256 + t] = p;
    Ph[(long)row * 256 + t] = (f16)p;
}

extern "C" void kernel_launch(void* const* d_in, const int* in_sizes, int n_in,
                              void* d_out, int out_size, void* d_ws, size_t ws_size,
                              hipStream_t stream) {
    const float* x  = (const float*)d_in[0];
    const float* Wq = (const float*)d_in[1];
    const float* bq = (const float*)d_in[2];
    const float* Wk = (const float*)d_in[3];
    const float* bk = (const float*)d_in[4];
    const float* Wv = (const float*)d_in[5];
    const float* bv = (const float*)d_in[6];
    const float* Wo = (const float*)d_in[7];
    const float* bo = (const float*)d_in[8];
    float* out   = (float*)d_out;
    float* probs = out + 50331648L;

    char* ws = (char*)d_ws;
    f16*   Xh   = (f16*)(ws + OFF_XH);
    float* Sp   = (float*)(ws + OFF_XH);   // alias: Xh dead after QKV
    f16*   CTXh = (f16*)(ws + OFF_XH);     // alias: Sp dead after softmax
    f16*   Qn   = (f16*)(ws + OFF_QN);
    f16*   Kn   = (f16*)(ws + OFF_KN);
    f16*   Vt2  = (f16*)(ws + OFF_VT);
    f16*   Wqkv = (f16*)(ws + OFF_WQKV);
    f16*   Woh  = (f16*)(ws + OFF_WO);
    float* bqkv = (float*)(ws + OFF_BQKV);
    f16*   Ph   = (f16*)(ws + OFF_PH);

    cast_f32_f16<<<24576, 256, 0, stream>>>(x,  Xh, 6291456);
    cast_f32_f16<<<288, 256, 0, stream>>>(Wq, Wqkv,           73728);
    cast_f32_f16<<<288, 256, 0, stream>>>(Wk, Wqkv +  589824, 73728);
    cast_f32_f16<<<288, 256, 0, stream>>>(Wv, Wqkv + 1179648, 73728);
    cast_f32_f16<<<288, 256, 0, stream>>>(Wo, Woh,            73728);
    pack_bias<<<1, 768, 0, stream>>>(bq, bk, bv, bqkv);

    // fused QKV projection: M=65536, N=2304, K=768
    gemm_big<MODE_QKV><<<dim3(9, 256), 512, 0, stream>>>(
        Xh, Wqkv, nullptr, Qn, bqkv, 768, 768, 768, 64);

    // scores: per (head, split) one 256x256 tile; K=1024 (16 r-slices)
    gemm_big<MODE_SPLIT><<<dim3(1, 1, 192), 512, 0, stream>>>(
        Qn, Kn, Sp, nullptr, nullptr, 768, 768, 1024, 196608);

    softmax_k<<<3072, 256, 0, stream>>>(Sp, probs, Ph);

    // context: per head M=256(i), N=16384(r,d), K=256(j)
    gemm_big<MODE_CTX><<<dim3(64, 1, 12), 512, 0, stream>>>(
        Ph, Vt2, nullptr, CTXh, nullptr, 256, 256, 256, 64);

    // output projection: M=65536, N=768, K=768
    gemm_big<MODE_OUT><<<dim3(3, 256), 512, 0, stream>>>(
        CTXh, Woh, out, nullptr, bo, 768, 768, 768, 64);
}